// Round 6
// baseline (2597.344 us; speedup 1.0000x reference)
//
#include <hip/hip_runtime.h>
#include <hip/hip_bf16.h>
#include <math.h>

#define PN 20000
#define DN 20000
#define SEQK 1024
#define EPPI 640000
#define EDDI 640000
#define EDTI 400000
#define NPAIRN 100000
#define RPB 128            // rows per bucket
#define NBUCK 157          // ceil(20000/128)

typedef float4 f4;
using bf16x8 = __attribute__((ext_vector_type(8))) __bf16;
using bf16x4 = __attribute__((ext_vector_type(4))) __bf16;
using f32x4v = __attribute__((ext_vector_type(4))) float;

__device__ __forceinline__ f4 ld4(const float* p) { return *reinterpret_cast<const f4*>(p); }
__device__ __forceinline__ f4 ldb4(const __bf16* p) {
  bf16x4 v = *reinterpret_cast<const bf16x4*>(p);
  return make_float4((float)v[0], (float)v[1], (float)v[2], (float)v[3]);
}
__device__ __forceinline__ void stb4(__bf16* p, f4 v) {
  bf16x4 o;
  o[0] = (__bf16)v.x; o[1] = (__bf16)v.y; o[2] = (__bf16)v.z; o[3] = (__bf16)v.w;
  *reinterpret_cast<bf16x4*>(p) = o;
}
__device__ __forceinline__ void acc4(f4& a, f4 b) { a.x+=b.x; a.y+=b.y; a.z+=b.z; a.w+=b.w; }
__device__ __forceinline__ void acc4s(f4& a, f4 b, float s) { a.x+=s*b.x; a.y+=s*b.y; a.z+=s*b.z; a.w+=s*b.w; }

__device__ __forceinline__ void wave_ln(f4& x) {
  float s  = x.x + x.y + x.z + x.w;
  float ss = x.x*x.x + x.y*x.y + x.z*x.z + x.w*x.w;
#pragma unroll
  for (int o = 32; o; o >>= 1) { s += __shfl_xor(s, o, 64); ss += __shfl_xor(ss, o, 64); }
  float m = s * (1.f/256.f);
  float v = ss * (1.f/256.f) - m*m;
  float r = rsqrtf(v + 1e-5f);
  x.x = (x.x-m)*r; x.y = (x.y-m)*r; x.z = (x.z-m)*r; x.w = (x.w-m)*r;
}

// ---------------- fp32 -> bf16 converters ----------------
struct WPack { const float* src[16]; __bf16* dst[16]; int n[16]; };
__global__ __launch_bounds__(256) void convert_weights(WPack p) {
  const int wi = blockIdx.y;
  const int n = p.n[wi];
  const float* s = p.src[wi];
  __bf16* d = p.dst[wi];
  for (int i = (blockIdx.x * 256 + threadIdx.x) * 4; i < n; i += gridDim.x * 256 * 4) {
    f4 v = ld4(s + i);
    stb4(d + i, v);
  }
}

struct EPack { const float* src[3]; __bf16* dst[3]; int n[3]; };
__global__ __launch_bounds__(256) void convert_emb(EPack p) {
  const int wi = blockIdx.y;
  const int n = p.n[wi];
  const float* s = p.src[wi];
  __bf16* d = p.dst[wi];
  for (int i = (blockIdx.x * 256 + threadIdx.x) * 4; i < n; i += gridDim.x * 256 * 4) {
    f4 v = ld4(s + i);
    stb4(d + i, v);
  }
}

// ---------------- MFMA GEMM: out[M,*] = X[M,K](bf16) @ Wt[N,K](bf16)^T (+bias)(+act) ------
__global__ __launch_bounds__(256) void gemm_mfma(
    const __bf16* __restrict__ X, const __bf16* __restrict__ Wt,
    const float* __restrict__ bias, __bf16* __restrict__ outb,
    int M, int K, int ostride, int act)
{
  const int tid = threadIdx.x;
  const int lane = tid & 63;
  const int w = tid >> 6;
  const int r0 = blockIdx.x * 64 + (w >> 1) * 32;
  const int c0 = blockIdx.y * 64 + (w & 1) * 32;
  const int l15 = lane & 15;
  const int lk = (lane >> 4) * 8;

  f32x4v acc[2][2];
#pragma unroll
  for (int m = 0; m < 2; ++m)
#pragma unroll
    for (int n = 0; n < 2; ++n) { acc[m][n][0]=0.f; acc[m][n][1]=0.f; acc[m][n][2]=0.f; acc[m][n][3]=0.f; }

  int ra = min(r0 + l15, M - 1);
  int rb = min(r0 + 16 + l15, M - 1);
  const __bf16* xa = X + (size_t)ra * K + lk;
  const __bf16* xb = X + (size_t)rb * K + lk;
  const __bf16* wa = Wt + (size_t)(c0 + l15) * K + lk;
  const __bf16* wc = Wt + (size_t)(c0 + 16 + l15) * K + lk;

  for (int k0 = 0; k0 < K; k0 += 32) {
    bf16x8 a0 = *reinterpret_cast<const bf16x8*>(xa + k0);
    bf16x8 a1 = *reinterpret_cast<const bf16x8*>(xb + k0);
    bf16x8 b0 = *reinterpret_cast<const bf16x8*>(wa + k0);
    bf16x8 b1 = *reinterpret_cast<const bf16x8*>(wc + k0);
    acc[0][0] = __builtin_amdgcn_mfma_f32_16x16x32_bf16(a0, b0, acc[0][0], 0, 0, 0);
    acc[0][1] = __builtin_amdgcn_mfma_f32_16x16x32_bf16(a0, b1, acc[0][1], 0, 0, 0);
    acc[1][0] = __builtin_amdgcn_mfma_f32_16x16x32_bf16(a1, b0, acc[1][0], 0, 0, 0);
    acc[1][1] = __builtin_amdgcn_mfma_f32_16x16x32_bf16(a1, b1, acc[1][1], 0, 0, 0);
  }

  const int rowbase = r0 + (lane >> 4) * 4;
#pragma unroll
  for (int m = 0; m < 2; ++m) {
#pragma unroll
    for (int i = 0; i < 4; ++i) {
      int row = rowbase + m * 16 + i;
      if (row >= M) continue;
#pragma unroll
      for (int n2 = 0; n2 < 2; ++n2) {
        int col = c0 + n2 * 16 + l15;
        float v = acc[m][n2][i];
        if (bias) v += bias[col];
        if (act == 1) v = fmaxf(v, 0.f);
        else if (act == 2) v = v > 0.f ? v : (expf(v) - 1.f);
        outb[(size_t)row * ostride + col] = (__bf16)v;
      }
    }
  }
}

// ---------------- bucketed CSR build (4 graphs via grid.y) ----------------
struct GPack {
  const int* src[4]; const int* dst[4]; int nE[4];
  int* col[4]; int* rowptr[4]; float* outdeg[4];  // dinvP,dinvD,icD,icP
  uint2* stg[4];
  int* bcnt;    // [4*NBUCK]
  int* bbase;   // [4*(NBUCK+1)]
  int* bcur;    // [4*NBUCK]
};

__global__ __launch_bounds__(256) void bucket_hist(GPack g) {
  int gi = blockIdx.y;
  int i = blockIdx.x * 256 + threadIdx.x;
  if (i < g.nE[gi]) atomicAdd(&g.bcnt[gi * NBUCK + (g.dst[gi][i] >> 7)], 1);
}

__global__ __launch_bounds__(64) void bucket_scan(GPack g) {
  int t = threadIdx.x;
  if (t < 4) {
    int run = 0;
    for (int b = 0; b < NBUCK; ++b) {
      g.bbase[t * (NBUCK + 1) + b] = run;
      g.bcur[t * NBUCK + b] = run;
      run += g.bcnt[t * NBUCK + b];
    }
    g.bbase[t * (NBUCK + 1) + NBUCK] = run;
  }
}

__global__ __launch_bounds__(256) void bucket_scatter(GPack g) {
  int gi = blockIdx.y;
  int i = blockIdx.x * 256 + threadIdx.x;
  if (i < g.nE[gi]) {
    int d = g.dst[gi][i];
    int b = d >> 7;
    int pos = atomicAdd(&g.bcur[gi * NBUCK + b], 1);
    g.stg[gi][pos] = make_uint2((unsigned)g.src[gi][i], (unsigned)d);
  }
}

__global__ __launch_bounds__(256) void bucket_csr(GPack g) {
  const int gi = blockIdx.y;
  const int b = blockIdx.x;
  const int base = g.bbase[gi * (NBUCK + 1) + b];
  const int cnt  = g.bbase[gi * (NBUCK + 1) + b + 1] - base;
  __shared__ int h[RPB], sc[RPB];
  const int t = threadIdx.x;
  if (t < RPB) h[t] = 0;
  __syncthreads();
  const uint2* st = g.stg[gi] + base;
  const int row0 = b * RPB;
  for (int i = t; i < cnt; i += 256) {
    int r = (int)st[i].y - row0;
    atomicAdd(&h[r], 1);
  }
  __syncthreads();
  if (t == 0) { int run = 0; for (int r = 0; r < RPB; ++r) { sc[r] = run; run += h[r]; } }
  __syncthreads();
  const int rows = min(RPB, PN - row0);
  if (t < rows) {
    g.rowptr[gi][row0 + t] = base + sc[t];
    float c = (float)h[t];
    g.outdeg[gi][row0 + t] = (gi < 2) ? rsqrtf(c + 1.f) : (1.f / fmaxf(c, 1.f));
  }
  if (b == 0 && t == 0) g.rowptr[gi][PN] = g.nE[gi];
  __syncthreads();
  if (t < RPB) h[t] = sc[t];   // reuse h as cursor
  __syncthreads();
  for (int i = t; i < cnt; i += 256) {
    uint2 e = st[i];
    int r = (int)e.y - row0;
    int pos = atomicAdd(&h[r], 1);
    g.col[gi][base + pos] = (int)e.x;
  }
}

// ---------------- fused GCN stage ----------------
__global__ __launch_bounds__(256) void gcn_combine(
    const int* __restrict__ rpG, const int* __restrict__ clG,
    const float* __restrict__ dinv,
    const __bf16* __restrict__ T, int tstride,
    const float* __restrict__ gb, const float* __restrict__ linb,
    const __bf16* __restrict__ L,
    const int* __restrict__ rpS, const int* __restrict__ clS,
    const float* __restrict__ ic, const __bf16* __restrict__ Pt,
    const float* __restrict__ lw, const float* __restrict__ lb,
    __bf16* __restrict__ out, int ostride, int n, int act)
{
  int row = (blockIdx.x * blockDim.x + threadIdx.x) >> 6;
  if (row >= n) return;
  int lane = threadIdx.x & 63;
  int o = lane * 4;
  float dd = dinv[row];

  f4 x = make_float4(0.f, 0.f, 0.f, 0.f);
  acc4s(x, ldb4(T + (size_t)row * tstride + o), dd * dd);   // self loop

  int beg = rpG[row], end = rpG[row + 1];
  int j = beg;
  for (; j + 3 < end; j += 4) {
    int s0 = clG[j], s1 = clG[j+1], s2 = clG[j+2], s3 = clG[j+3];
    float n0 = dd * dinv[s0], n1 = dd * dinv[s1], n2 = dd * dinv[s2], n3 = dd * dinv[s3];
    f4 t0 = ldb4(T + (size_t)s0 * tstride + o);
    f4 t1 = ldb4(T + (size_t)s1 * tstride + o);
    f4 t2 = ldb4(T + (size_t)s2 * tstride + o);
    f4 t3 = ldb4(T + (size_t)s3 * tstride + o);
    acc4s(x, t0, n0); acc4s(x, t1, n1); acc4s(x, t2, n2); acc4s(x, t3, n3);
  }
  for (; j < end; ++j) {
    int s0 = clG[j];
    acc4s(x, ldb4(T + (size_t)s0 * tstride + o), dd * dinv[s0]);
  }

  if (gb)   acc4(x, ld4(gb + o));
  if (linb) acc4(x, ld4(linb + o));
  if (L)    acc4(x, ldb4(L + (size_t)row * tstride + o));

  if (rpS) {
    f4 s = make_float4(0.f, 0.f, 0.f, 0.f);
    int sb = rpS[row], se = rpS[row + 1];
    int k = sb;
    for (; k + 3 < se; k += 4) {
      int s0 = clS[k], s1 = clS[k+1], s2 = clS[k+2], s3 = clS[k+3];
      f4 t0 = ldb4(Pt + (size_t)s0 * 256 + o);
      f4 t1 = ldb4(Pt + (size_t)s1 * 256 + o);
      f4 t2 = ldb4(Pt + (size_t)s2 * 256 + o);
      f4 t3 = ldb4(Pt + (size_t)s3 * 256 + o);
      acc4(s, t0); acc4(s, t1); acc4(s, t2); acc4(s, t3);
    }
    for (; k < se; ++k) acc4(s, ldb4(Pt + (size_t)clS[k] * 256 + o));
    acc4s(x, s, ic[row]);
  }

  wave_ln(x);
  if (lw) {
    f4 w = ld4(lw + o), b = ld4(lb + o);
    x.x = x.x*w.x + b.x; x.y = x.y*w.y + b.y; x.z = x.z*w.z + b.z; x.w = x.w*w.w + b.w;
  }
  if (act == 1) {
    x.x = fmaxf(x.x, 0.f); x.y = fmaxf(x.y, 0.f); x.z = fmaxf(x.z, 0.f); x.w = fmaxf(x.w, 0.f);
  }
  stb4(out + (size_t)row * ostride + o, x);
}

// ---------------- fp = elu(LN(x_seq)) from bf16 ----------------
__global__ __launch_bounds__(256) void ln_elu(const __bf16* __restrict__ in, __bf16* __restrict__ out, int n) {
  int row = (blockIdx.x * blockDim.x + threadIdx.x) >> 6;
  if (row >= n) return;
  int lane = threadIdx.x & 63;
  int o = lane * 4;
  f4 x = ldb4(in + (size_t)row * 256 + o);
  wave_ln(x);
  x.x = x.x > 0.f ? x.x : expf(x.x)-1.f;
  x.y = x.y > 0.f ? x.y : expf(x.y)-1.f;
  x.z = x.z > 0.f ? x.z : expf(x.z)-1.f;
  x.w = x.w > 0.f ? x.w : expf(x.w)-1.f;
  stb4(out + (size_t)row * 256 + o, x);
}

// ---------------- pair epilogue: PK interleaved [node][slot0..3][256] ----------------
// slot0=x1, slot1=xfp, slot2=p2, slot3=xskip
__global__ __launch_bounds__(256) void pair_kernel(
    const __bf16* __restrict__ PK,
    const int* __restrict__ idx1, const int* __restrict__ idx2,
    const float* __restrict__ wR, const float* __restrict__ wI,
    float* __restrict__ out, int npair)
{
  int wid = (blockIdx.x * blockDim.x + threadIdx.x) >> 6;
  if (wid >= npair) return;
  int lane = threadIdx.x & 63;
  int f = lane * 4;
  const __bf16* r1 = PK + (size_t)idx1[wid] * 1024;
  const __bf16* r2 = PK + (size_t)idx2[wid] * 1024;

  f4 R1 = ldb4(r1 + f);        acc4(R1, ldb4(r2 + 256 + f)); wave_ln(R1);
  f4 I1 = ldb4(r1 + 512 + f);  acc4(I1, ldb4(r2 + 768 + f)); wave_ln(I1);
  f4 R2 = ldb4(r1 + 768 + f);  acc4(R2, ldb4(r2 + 512 + f)); wave_ln(R2);
  f4 I2 = ldb4(r1 + 256 + f);  acc4(I2, ldb4(r2 + f));       wave_ln(I2);

  f4 R, I;
  R.x = R1.x*R2.x - I1.x*I2.x;  I.x = R1.x*I2.x + I1.x*R2.x;
  R.y = R1.y*R2.y - I1.y*I2.y;  I.y = R1.y*I2.y + I1.y*R2.y;
  R.z = R1.z*R2.z - I1.z*I2.z;  I.z = R1.z*I2.z + I1.z*R2.z;
  R.w = R1.w*R2.w - I1.w*I2.w;  I.w = R1.w*I2.w + I1.w*R2.w;
  wave_ln(R); wave_ln(I);

  f4 wr = ld4(wR + f), wi = ld4(wI + f);
  float r_ = R.x*wr.x + I.x*wi.x + R.y*wr.y + I.y*wi.y
           + R.z*wr.z + I.z*wi.z + R.w*wr.w + I.w*wi.w;
  float i_ = I.x*wr.x - R.x*wi.x + I.y*wr.y - R.y*wi.y
           + I.z*wr.z - R.z*wi.z + I.w*wr.w - R.w*wi.w;
  float t = r_ + i_;
#pragma unroll
  for (int o = 32; o; o >>= 1) t += __shfl_xor(t, o, 64);
  if (lane == 0) out[wid] = 1.f / (1.f + expf(-t));
}

extern "C" void kernel_launch(void* const* d_in, const int* in_sizes, int n_in,
                              void* d_out, int out_size, void* d_ws, size_t ws_size,
                              hipStream_t stream) {
  (void)in_sizes; (void)n_in; (void)out_size; (void)ws_size;
  const float* seq        = (const float*)d_in[0];
  const int*   ppi        = (const int*)d_in[1];
  const int*   ddi        = (const int*)d_in[2];
  const int*   dti        = (const int*)d_in[3];
  const int*   idx1       = (const int*)d_in[4];
  const int*   idx2       = (const int*)d_in[5];
  const float* seq_init_W = (const float*)d_in[6];
  const float* gs1_gcn_W  = (const float*)d_in[7];
  const float* gs1_gcn_b  = (const float*)d_in[8];
  const float* gs1_lin_W  = (const float*)d_in[9];
  const float* gs1_ln_w   = (const float*)d_in[10];
  const float* gs1_ln_b   = (const float*)d_in[11];
  const float* gs2_gcn_W  = (const float*)d_in[12];
  const float* gs2_gcn_b  = (const float*)d_in[13];
  const float* gs2_lin_W  = (const float*)d_in[14];
  const float* gs2_ln_w   = (const float*)d_in[15];
  const float* gs2_ln_b   = (const float*)d_in[16];
  const float* drug_emb   = (const float*)d_in[17];
  const float* prot_emb   = (const float*)d_in[18];
  const float* pp1_W = (const float*)d_in[19]; const float* pp1_b = (const float*)d_in[20];
  const float* td1_W = (const float*)d_in[21]; const float* td1_b = (const float*)d_in[22];
  const float* pr1_W = (const float*)d_in[23]; const float* pr1_b = (const float*)d_in[24];
  const float* dd1_W = (const float*)d_in[25]; const float* dd1_b = (const float*)d_in[26];
  const float* dt1_W = (const float*)d_in[27]; const float* dt1_b = (const float*)d_in[28];
  const float* dr1_W = (const float*)d_in[29]; const float* dr1_b = (const float*)d_in[30];
  const float* pp2_W = (const float*)d_in[31]; const float* pp2_b = (const float*)d_in[32];
  const float* td2_W = (const float*)d_in[33]; const float* td2_b = (const float*)d_in[34];
  const float* pr2_W = (const float*)d_in[35]; const float* pr2_b = (const float*)d_in[36];
  const float* seq_fc_W  = (const float*)d_in[43];
  const float* skip_fc_W = (const float*)d_in[44];
  const float* wR = (const float*)d_in[45];
  const float* wI = (const float*)d_in[46];
  float* outp = (float*)d_out;

  // ---------------- workspace layout ----------------
  char* base = (char*)d_ws;
  // staging first (8B aligned)
  uint2* stgP  = (uint2*)base;                       // EPPI
  uint2* stgD  = stgP + EPPI;                        // EDDI
  uint2* stgTD = stgD + EDDI;                        // EDTI
  uint2* stgTP = stgTD + EDTI;                       // EDTI
  int* colP  = (int*)(stgTP + EDTI);
  int* colD  = colP + EPPI;
  int* colTD = colD + EDDI;
  int* colTP = colTD + EDTI;
  int* rowptrP  = colTP + EDTI;
  int* rowptrD  = rowptrP + PN + 1;
  int* rowptrTD = rowptrD + PN + 1;
  int* rowptrTP = rowptrTD + PN + 1;
  float* dinvP = (float*)(rowptrTP + PN + 1);
  float* dinvD = dinvP + PN;
  float* icD   = dinvD + PN;
  float* icP   = icD + PN;
  int* bcnt  = (int*)(icP + PN);      // 4*NBUCK
  int* bbase = bcnt + 4 * NBUCK;      // 4*(NBUCK+1)
  int* bcur  = bbase + 4 * (NBUCK + 1);

  unsigned long long waddr = (unsigned long long)(bcur + 4 * NBUCK);
  waddr = (waddr + 63ULL) & ~63ULL;
  __bf16* wb = (__bf16*)waddr;
  __bf16* Wseq  = wb;                           // [256,1024]
  __bf16* pair0 = Wseq + 256*1024;              // each pair [512,256]
  __bf16* pair1 = pair0 + 512*256;
  __bf16* pair2 = pair1 + 512*256;
  __bf16* pair3 = pair2 + 512*256;
  __bf16* pair4 = pair3 + 512*256;
  __bf16* sing  = pair4 + 512*256;
  __bf16* Wdt1  = sing;
  __bf16* Wtd1  = sing + 65536;
  __bf16* Wtd2  = sing + 2*65536;
  __bf16* Wsfc  = sing + 3*65536;
  __bf16* Wskp  = sing + 4*65536;
  const size_t NB = (size_t)PN * 256;
  __bf16* Eseq  = sing + 5*65536;               // [20000,1024]
  __bf16* Ed    = Eseq + (size_t)PN*SEQK;
  __bf16* Ep    = Ed + NB;
  __bf16* TL    = Ep + NB;                      // [20000,512]
  __bf16* B0    = TL + (size_t)PN*512;          // x_seq
  __bf16* B2    = B0 + NB;                      // h -> d
  __bf16* B4    = B2 + NB;                      // proj -> fp
  __bf16* B5    = B4 + NB;                      // p
  __bf16* PK    = B5 + NB;                      // [20000][4*256]: x1 | xfp | p2 | xskip

  const dim3 blk(256);
  const dim3 g256(313, 4);
  const dim3 g512(313, 8);
  const dim3 rgrid((PN + 3) / 4);
  const dim3 egrid((EPPI + 255) / 256, 4);
  const dim3 bgrid(NBUCK, 4);

  auto GEMM = [&](const __bf16* X, const __bf16* Wt, const float* bias,
                  __bf16* outb, int K, int ostride, int act, dim3 grid) {
    hipLaunchKernelGGL(gemm_mfma, grid, blk, 0, stream, X, Wt, bias, outb, PN, K, ostride, act);
  };
  auto STAGE = [&](const int* rpG, const int* clG, const float* dv,
                   const float* gb, const float* linb,
                   const int* rpS, const int* clS, const float* ic, const __bf16* Pt,
                   const float* lw, const float* lb, __bf16* o, int ostr, int n, int act) {
    hipLaunchKernelGGL(gcn_combine, rgrid, blk, 0, stream, rpG, clG, dv, TL, 512, gb, linb,
                       TL + 256, rpS, clS, ic, Pt, lw, lb, o, ostr, n, act);
  };

  // ---- converts ----
  {
    WPack p;
    const float* srcs[16] = { seq_init_W, gs1_gcn_W, gs1_lin_W, gs2_gcn_W, gs2_lin_W,
                              dd1_W, dr1_W, pp1_W, pr1_W, pp2_W, pr2_W,
                              dt1_W, td1_W, td2_W, seq_fc_W, skip_fc_W };
    __bf16* dsts[16] = { Wseq, pair0, pair0 + 65536, pair1, pair1 + 65536,
                         pair2, pair2 + 65536, pair3, pair3 + 65536, pair4, pair4 + 65536,
                         Wdt1, Wtd1, Wtd2, Wsfc, Wskp };
    for (int i = 0; i < 16; ++i) { p.src[i] = srcs[i]; p.dst[i] = dsts[i]; p.n[i] = (i == 0) ? 256*1024 : 256*256; }
    hipLaunchKernelGGL(convert_weights, dim3(16, 16), blk, 0, stream, p);
  }
  {
    EPack p;
    p.src[0] = seq;      p.dst[0] = Eseq; p.n[0] = PN * SEQK;
    p.src[1] = drug_emb; p.dst[1] = Ed;   p.n[1] = PN * 256;
    p.src[2] = prot_emb; p.dst[2] = Ep;   p.n[2] = PN * 256;
    hipLaunchKernelGGL(convert_emb, dim3(2048, 3), blk, 0, stream, p);
  }

  // ---- bucketed CSR build ----
  GPack g;
  g.src[0] = ppi;        g.dst[0] = ppi + EPPI; g.nE[0] = EPPI;
  g.src[1] = ddi;        g.dst[1] = ddi + EDDI; g.nE[1] = EDDI;
  g.src[2] = dti + EDTI; g.dst[2] = dti;        g.nE[2] = EDTI;
  g.src[3] = dti;        g.dst[3] = dti + EDTI; g.nE[3] = EDTI;
  g.col[0] = colP;  g.col[1] = colD;  g.col[2] = colTD;  g.col[3] = colTP;
  g.rowptr[0] = rowptrP; g.rowptr[1] = rowptrD; g.rowptr[2] = rowptrTD; g.rowptr[3] = rowptrTP;
  g.outdeg[0] = dinvP; g.outdeg[1] = dinvD; g.outdeg[2] = icD; g.outdeg[3] = icP;
  g.stg[0] = stgP; g.stg[1] = stgD; g.stg[2] = stgTD; g.stg[3] = stgTP;
  g.bcnt = bcnt; g.bbase = bbase; g.bcur = bcur;

  hipMemsetAsync(bcnt, 0, 4 * NBUCK * sizeof(int), stream);
  hipLaunchKernelGGL(bucket_hist, egrid, blk, 0, stream, g);
  hipLaunchKernelGGL(bucket_scan, dim3(1), dim3(64), 0, stream, g);
  hipLaunchKernelGGL(bucket_scatter, egrid, blk, 0, stream, g);
  hipLaunchKernelGGL(bucket_csr, bgrid, blk, 0, stream, g);

  // ---- P1: x_seq = relu(Eseq @ Wseq^T) -> B0 ----
  GEMM(Eseq, Wseq, nullptr, B0, SEQK, 256, 1, g256);

  // ---- P2 (gs1): h -> B2 ----
  GEMM(B0, pair0, nullptr, TL, 256, 512, 0, g512);
  STAGE(rowptrP, colP, dinvP, gs1_gcn_b, nullptr, nullptr, nullptr, nullptr, nullptr,
        gs1_ln_w, gs1_ln_b, B2, 256, PN, 1);

  // ---- P3 (gs2): x1 -> PK slot0 ----
  GEMM(B2, pair1, nullptr, TL, 256, 512, 0, g512);
  STAGE(rowptrP, colP, dinvP, gs2_gcn_b, nullptr, nullptr, nullptr, nullptr, nullptr,
        gs2_ln_w, gs2_ln_b, PK + 0, 1024, PN, 0);

  // ---- P4d (drug layer 1): d -> B2 ----
  GEMM(Ed, pair2, nullptr, TL, 256, 512, 0, g512);         // dd1 | dr1
  GEMM(Ep, Wdt1, dt1_b, B4, 256, 256, 0, g256);            // proj_p
  STAGE(rowptrD, colD, dinvD, dd1_b, dr1_b, rowptrTD, colTD, icD, B4,
        nullptr, nullptr, B2, 256, DN, 1);

  // ---- P4p (protein layer 1): p -> B5 ----
  GEMM(Ep, pair3, nullptr, TL, 256, 512, 0, g512);         // pp1 | pr1
  GEMM(Ed, Wtd1, td1_b, B4, 256, 256, 0, g256);            // proj_d
  STAGE(rowptrP, colP, dinvP, pp1_b, pr1_b, rowptrTP, colTP, icP, B4,
        nullptr, nullptr, B5, 256, PN, 1);

  // ---- P5 (protein layer 2): p2 -> PK slot2 ----
  GEMM(B2, Wtd2, td2_b, B4, 256, 256, 0, g256);            // proj (td2) from d
  GEMM(B5, pair4, nullptr, TL, 256, 512, 0, g512);         // pp2 | pr2 from p
  STAGE(rowptrP, colP, dinvP, pp2_b, pr2_b, rowptrTP, colTP, icP, B4,
        nullptr, nullptr, PK + 512, 1024, PN, 0);

  // ---- P6: fuse precompute ----
  hipLaunchKernelGGL(ln_elu, rgrid, blk, 0, stream, B0, B4, PN);  // fp
  GEMM(B4, Wsfc, nullptr, PK + 256, 256, 1024, 2, g256);          // x_fp -> slot1
  GEMM(Ep, Wskp, nullptr, PK + 768, 256, 1024, 0, g256);          // x_skip -> slot3

  // ---- P7: pair epilogue ----
  hipLaunchKernelGGL(pair_kernel, dim3((NPAIRN + 3) / 4), blk, 0, stream,
                     PK, idx1, idx2, wR, wI, outp, NPAIRN);
}

// Round 7
// 899.757 us; speedup vs baseline: 2.8867x; 2.8867x over previous
//
#include <hip/hip_runtime.h>
#include <hip/hip_bf16.h>
#include <math.h>

#define PN 20000
#define DN 20000
#define SEQK 1024
#define EPPI 640000
#define EDDI 640000
#define EDTI 400000
#define NPAIRN 100000
#define RPB 128            // rows per bucket
#define NBUCK 157          // ceil(20000/128)
#define CH 4096            // edges per sort block
#define NBLKMAX 157        // ceil(640000/4096)

typedef float4 f4;
using bf16x8 = __attribute__((ext_vector_type(8))) __bf16;
using bf16x4 = __attribute__((ext_vector_type(4))) __bf16;
using f32x4v = __attribute__((ext_vector_type(4))) float;

__device__ __forceinline__ f4 ld4(const float* p) { return *reinterpret_cast<const f4*>(p); }
__device__ __forceinline__ f4 ldb4(const __bf16* p) {
  bf16x4 v = *reinterpret_cast<const bf16x4*>(p);
  return make_float4((float)v[0], (float)v[1], (float)v[2], (float)v[3]);
}
__device__ __forceinline__ void stb4(__bf16* p, f4 v) {
  bf16x4 o;
  o[0] = (__bf16)v.x; o[1] = (__bf16)v.y; o[2] = (__bf16)v.z; o[3] = (__bf16)v.w;
  *reinterpret_cast<bf16x4*>(p) = o;
}
__device__ __forceinline__ void acc4(f4& a, f4 b) { a.x+=b.x; a.y+=b.y; a.z+=b.z; a.w+=b.w; }
__device__ __forceinline__ void acc4s(f4& a, f4 b, float s) { a.x+=s*b.x; a.y+=s*b.y; a.z+=s*b.z; a.w+=s*b.w; }

__device__ __forceinline__ void wave_ln(f4& x) {
  float s  = x.x + x.y + x.z + x.w;
  float ss = x.x*x.x + x.y*x.y + x.z*x.z + x.w*x.w;
#pragma unroll
  for (int o = 32; o; o >>= 1) { s += __shfl_xor(s, o, 64); ss += __shfl_xor(ss, o, 64); }
  float m = s * (1.f/256.f);
  float v = ss * (1.f/256.f) - m*m;
  float r = rsqrtf(v + 1e-5f);
  x.x = (x.x-m)*r; x.y = (x.y-m)*r; x.z = (x.z-m)*r; x.w = (x.w-m)*r;
}

// ---------------- fp32 -> bf16 converters ----------------
struct WPack { const float* src[16]; __bf16* dst[16]; int n[16]; };
__global__ __launch_bounds__(256) void convert_weights(WPack p) {
  const int wi = blockIdx.y;
  const int n = p.n[wi];
  const float* s = p.src[wi];
  __bf16* d = p.dst[wi];
  for (int i = (blockIdx.x * 256 + threadIdx.x) * 4; i < n; i += gridDim.x * 256 * 4) {
    f4 v = ld4(s + i);
    stb4(d + i, v);
  }
}

struct EPack { const float* src[3]; __bf16* dst[3]; int n[3]; };
__global__ __launch_bounds__(256) void convert_emb(EPack p) {
  const int wi = blockIdx.y;
  const int n = p.n[wi];
  const float* s = p.src[wi];
  __bf16* d = p.dst[wi];
  for (int i = (blockIdx.x * 256 + threadIdx.x) * 4; i < n; i += gridDim.x * 256 * 4) {
    f4 v = ld4(s + i);
    stb4(d + i, v);
  }
}

// ---------------- MFMA GEMM ----------------
__global__ __launch_bounds__(256) void gemm_mfma(
    const __bf16* __restrict__ X, const __bf16* __restrict__ Wt,
    const float* __restrict__ bias, __bf16* __restrict__ outb,
    int M, int K, int ostride, int act)
{
  const int tid = threadIdx.x;
  const int lane = tid & 63;
  const int w = tid >> 6;
  const int r0 = blockIdx.x * 64 + (w >> 1) * 32;
  const int c0 = blockIdx.y * 64 + (w & 1) * 32;
  const int l15 = lane & 15;
  const int lk = (lane >> 4) * 8;

  f32x4v acc[2][2];
#pragma unroll
  for (int m = 0; m < 2; ++m)
#pragma unroll
    for (int n = 0; n < 2; ++n) { acc[m][n][0]=0.f; acc[m][n][1]=0.f; acc[m][n][2]=0.f; acc[m][n][3]=0.f; }

  int ra = min(r0 + l15, M - 1);
  int rb = min(r0 + 16 + l15, M - 1);
  const __bf16* xa = X + (size_t)ra * K + lk;
  const __bf16* xb = X + (size_t)rb * K + lk;
  const __bf16* wa = Wt + (size_t)(c0 + l15) * K + lk;
  const __bf16* wc = Wt + (size_t)(c0 + 16 + l15) * K + lk;

  for (int k0 = 0; k0 < K; k0 += 32) {
    bf16x8 a0 = *reinterpret_cast<const bf16x8*>(xa + k0);
    bf16x8 a1 = *reinterpret_cast<const bf16x8*>(xb + k0);
    bf16x8 b0 = *reinterpret_cast<const bf16x8*>(wa + k0);
    bf16x8 b1 = *reinterpret_cast<const bf16x8*>(wc + k0);
    acc[0][0] = __builtin_amdgcn_mfma_f32_16x16x32_bf16(a0, b0, acc[0][0], 0, 0, 0);
    acc[0][1] = __builtin_amdgcn_mfma_f32_16x16x32_bf16(a0, b1, acc[0][1], 0, 0, 0);
    acc[1][0] = __builtin_amdgcn_mfma_f32_16x16x32_bf16(a1, b0, acc[1][0], 0, 0, 0);
    acc[1][1] = __builtin_amdgcn_mfma_f32_16x16x32_bf16(a1, b1, acc[1][1], 0, 0, 0);
  }

  const int rowbase = r0 + (lane >> 4) * 4;
#pragma unroll
  for (int m = 0; m < 2; ++m) {
#pragma unroll
    for (int i = 0; i < 4; ++i) {
      int row = rowbase + m * 16 + i;
      if (row >= M) continue;
#pragma unroll
      for (int n2 = 0; n2 < 2; ++n2) {
        int col = c0 + n2 * 16 + l15;
        float v = acc[m][n2][i];
        if (bias) v += bias[col];
        if (act == 1) v = fmaxf(v, 0.f);
        else if (act == 2) v = v > 0.f ? v : (expf(v) - 1.f);
        outb[(size_t)row * ostride + col] = (__bf16)v;
      }
    }
  }
}

// ---------------- contention-free two-level counting-sort CSR build ----------------
struct GPack {
  const int* src[4]; const int* dst[4]; int nE[4];
  int* col[4]; int* rowptr[4]; float* outdeg[4];  // dinvP,dinvD,icD,icP
  unsigned* stg[4];
  int* bh;      // [4][NBUCK][NBLKMAX] counts -> exclusive scan
  int* bbase;   // [4][NBUCK+1]
};

// Pass A: per-block LDS histogram over buckets, write bh[gi][b][blk]
__global__ __launch_bounds__(256) void sort_hist(GPack g) {
  __shared__ int h[NBUCK];
  const int gi = blockIdx.y, blk = blockIdx.x;
  const int t = threadIdx.x;
  for (int i = t; i < NBUCK; i += 256) h[i] = 0;
  __syncthreads();
  const int base = blk * CH, nE = g.nE[gi];
  const int* dst = g.dst[gi];
#pragma unroll
  for (int i = 0; i < CH / 256; ++i) {
    int e = base + i * 256 + t;
    if (e < nE) atomicAdd(&h[dst[e] >> 7], 1);
  }
  __syncthreads();
  int* bh = g.bh + (size_t)gi * NBUCK * NBLKMAX;
  for (int i = t; i < NBUCK; i += 256) bh[i * NBLKMAX + blk] = h[i];
}

// Pass B: exclusive scan of bh[gi][.][.] flattened (bucket-major); emit bbase
__global__ __launch_bounds__(1024) void sort_scan(GPack g) {
  __shared__ int sums[1024];
  const int gi = blockIdx.y;
  int* bh = g.bh + (size_t)gi * NBUCK * NBLKMAX;
  int* bbase = g.bbase + gi * (NBUCK + 1);
  const int L = NBUCK * NBLKMAX;
  const int t = threadIdx.x;
  const int chunk = (L + 1023) / 1024;
  const int b = t * chunk;
  const int e = min(b + chunk, L);
  int s = 0;
  for (int i = b; i < e; ++i) s += bh[i];
  sums[t] = s;
  __syncthreads();
  for (int o = 1; o < 1024; o <<= 1) {
    int u = (t >= o) ? sums[t - o] : 0;
    __syncthreads();
    sums[t] += u;
    __syncthreads();
  }
  int run = sums[t] - s;
  for (int i = b; i < e; ++i) {
    if (i % NBLKMAX == 0) bbase[i / NBLKMAX] = run;
    int old = bh[i];
    bh[i] = run;
    run += old;
  }
  if (t == 0) bbase[NBUCK] = g.nE[gi];
}

// Pass C: scatter packed (src<<7)|rowInBucket to exact positions; LDS cursors, no global atomics
__global__ __launch_bounds__(256) void sort_scatter(GPack g) {
  __shared__ int cur[NBUCK];
  const int gi = blockIdx.y, blk = blockIdx.x;
  const int t = threadIdx.x;
  const int* bh = g.bh + (size_t)gi * NBUCK * NBLKMAX;
  for (int i = t; i < NBUCK; i += 256) cur[i] = bh[i * NBLKMAX + blk];
  __syncthreads();
  const int base = blk * CH, nE = g.nE[gi];
  const int* src = g.src[gi];
  const int* dst = g.dst[gi];
  unsigned* stg = g.stg[gi];
#pragma unroll
  for (int i = 0; i < CH / 256; ++i) {
    int e = base + i * 256 + t;
    if (e < nE) {
      int d = dst[e];
      int bkt = d >> 7;
      int pos = atomicAdd(&cur[bkt], 1);   // LDS atomic
      stg[pos] = ((unsigned)src[e] << 7) | (unsigned)(d & 127);
    }
  }
}

// Pass D: per-bucket CSR finalize in LDS
__global__ __launch_bounds__(256) void bucket_csr(GPack g) {
  const int gi = blockIdx.y;
  const int b = blockIdx.x;
  const int base = g.bbase[gi * (NBUCK + 1) + b];
  const int cnt  = g.bbase[gi * (NBUCK + 1) + b + 1] - base;
  __shared__ int h[RPB], sc[RPB];
  const int t = threadIdx.x;
  if (t < RPB) h[t] = 0;
  __syncthreads();
  const unsigned* st = g.stg[gi] + base;
  const int row0 = b * RPB;
  for (int i = t; i < cnt; i += 256) atomicAdd(&h[st[i] & 127u], 1);
  __syncthreads();
  if (t == 0) { int run = 0; for (int r = 0; r < RPB; ++r) { sc[r] = run; run += h[r]; } }
  __syncthreads();
  const int rows = min(RPB, PN - row0);
  if (t < rows) {
    g.rowptr[gi][row0 + t] = base + sc[t];
    float c = (float)h[t];
    g.outdeg[gi][row0 + t] = (gi < 2) ? rsqrtf(c + 1.f) : (1.f / fmaxf(c, 1.f));
  }
  if (b == 0 && t == 0) g.rowptr[gi][PN] = g.nE[gi];
  __syncthreads();
  if (t < RPB) h[t] = sc[t];
  __syncthreads();
  for (int i = t; i < cnt; i += 256) {
    unsigned v = st[i];
    int pos = atomicAdd(&h[v & 127u], 1);
    g.col[gi][base + pos] = (int)(v >> 7);
  }
}

// ---------------- fused GCN stage ----------------
__global__ __launch_bounds__(256) void gcn_combine(
    const int* __restrict__ rpG, const int* __restrict__ clG,
    const float* __restrict__ dinv,
    const __bf16* __restrict__ T, int tstride,
    const float* __restrict__ gb, const float* __restrict__ linb,
    const __bf16* __restrict__ L,
    const int* __restrict__ rpS, const int* __restrict__ clS,
    const float* __restrict__ ic, const __bf16* __restrict__ Pt,
    const float* __restrict__ lw, const float* __restrict__ lb,
    __bf16* __restrict__ out, int ostride, int n, int act)
{
  int row = (blockIdx.x * blockDim.x + threadIdx.x) >> 6;
  if (row >= n) return;
  int lane = threadIdx.x & 63;
  int o = lane * 4;
  float dd = dinv[row];

  f4 x = make_float4(0.f, 0.f, 0.f, 0.f);
  acc4s(x, ldb4(T + (size_t)row * tstride + o), dd * dd);   // self loop

  int beg = rpG[row], end = rpG[row + 1];
  int j = beg;
  for (; j + 3 < end; j += 4) {
    int s0 = clG[j], s1 = clG[j+1], s2 = clG[j+2], s3 = clG[j+3];
    float n0 = dd * dinv[s0], n1 = dd * dinv[s1], n2 = dd * dinv[s2], n3 = dd * dinv[s3];
    f4 t0 = ldb4(T + (size_t)s0 * tstride + o);
    f4 t1 = ldb4(T + (size_t)s1 * tstride + o);
    f4 t2 = ldb4(T + (size_t)s2 * tstride + o);
    f4 t3 = ldb4(T + (size_t)s3 * tstride + o);
    acc4s(x, t0, n0); acc4s(x, t1, n1); acc4s(x, t2, n2); acc4s(x, t3, n3);
  }
  for (; j < end; ++j) {
    int s0 = clG[j];
    acc4s(x, ldb4(T + (size_t)s0 * tstride + o), dd * dinv[s0]);
  }

  if (gb)   acc4(x, ld4(gb + o));
  if (linb) acc4(x, ld4(linb + o));
  if (L)    acc4(x, ldb4(L + (size_t)row * tstride + o));

  if (rpS) {
    f4 s = make_float4(0.f, 0.f, 0.f, 0.f);
    int sb = rpS[row], se = rpS[row + 1];
    int k = sb;
    for (; k + 3 < se; k += 4) {
      int s0 = clS[k], s1 = clS[k+1], s2 = clS[k+2], s3 = clS[k+3];
      f4 t0 = ldb4(Pt + (size_t)s0 * 256 + o);
      f4 t1 = ldb4(Pt + (size_t)s1 * 256 + o);
      f4 t2 = ldb4(Pt + (size_t)s2 * 256 + o);
      f4 t3 = ldb4(Pt + (size_t)s3 * 256 + o);
      acc4(s, t0); acc4(s, t1); acc4(s, t2); acc4(s, t3);
    }
    for (; k < se; ++k) acc4(s, ldb4(Pt + (size_t)clS[k] * 256 + o));
    acc4s(x, s, ic[row]);
  }

  wave_ln(x);
  if (lw) {
    f4 w = ld4(lw + o), b = ld4(lb + o);
    x.x = x.x*w.x + b.x; x.y = x.y*w.y + b.y; x.z = x.z*w.z + b.z; x.w = x.w*w.w + b.w;
  }
  if (act == 1) {
    x.x = fmaxf(x.x, 0.f); x.y = fmaxf(x.y, 0.f); x.z = fmaxf(x.z, 0.f); x.w = fmaxf(x.w, 0.f);
  }
  stb4(out + (size_t)row * ostride + o, x);
}

// ---------------- fp = elu(LN(x_seq)) from bf16 ----------------
__global__ __launch_bounds__(256) void ln_elu(const __bf16* __restrict__ in, __bf16* __restrict__ out, int n) {
  int row = (blockIdx.x * blockDim.x + threadIdx.x) >> 6;
  if (row >= n) return;
  int lane = threadIdx.x & 63;
  int o = lane * 4;
  f4 x = ldb4(in + (size_t)row * 256 + o);
  wave_ln(x);
  x.x = x.x > 0.f ? x.x : expf(x.x)-1.f;
  x.y = x.y > 0.f ? x.y : expf(x.y)-1.f;
  x.z = x.z > 0.f ? x.z : expf(x.z)-1.f;
  x.w = x.w > 0.f ? x.w : expf(x.w)-1.f;
  stb4(out + (size_t)row * 256 + o, x);
}

// ---------------- pair epilogue: PK interleaved [node][slot0..3][256] ----------------
__global__ __launch_bounds__(256) void pair_kernel(
    const __bf16* __restrict__ PK,
    const int* __restrict__ idx1, const int* __restrict__ idx2,
    const float* __restrict__ wR, const float* __restrict__ wI,
    float* __restrict__ out, int npair)
{
  int wid = (blockIdx.x * blockDim.x + threadIdx.x) >> 6;
  if (wid >= npair) return;
  int lane = threadIdx.x & 63;
  int f = lane * 4;
  const __bf16* r1 = PK + (size_t)idx1[wid] * 1024;
  const __bf16* r2 = PK + (size_t)idx2[wid] * 1024;

  f4 R1 = ldb4(r1 + f);        acc4(R1, ldb4(r2 + 256 + f)); wave_ln(R1);
  f4 I1 = ldb4(r1 + 512 + f);  acc4(I1, ldb4(r2 + 768 + f)); wave_ln(I1);
  f4 R2 = ldb4(r1 + 768 + f);  acc4(R2, ldb4(r2 + 512 + f)); wave_ln(R2);
  f4 I2 = ldb4(r1 + 256 + f);  acc4(I2, ldb4(r2 + f));       wave_ln(I2);

  f4 R, I;
  R.x = R1.x*R2.x - I1.x*I2.x;  I.x = R1.x*I2.x + I1.x*R2.x;
  R.y = R1.y*R2.y - I1.y*I2.y;  I.y = R1.y*I2.y + I1.y*R2.y;
  R.z = R1.z*R2.z - I1.z*I2.z;  I.z = R1.z*I2.z + I1.z*R2.z;
  R.w = R1.w*R2.w - I1.w*I2.w;  I.w = R1.w*I2.w + I1.w*R2.w;
  wave_ln(R); wave_ln(I);

  f4 wr = ld4(wR + f), wi = ld4(wI + f);
  float r_ = R.x*wr.x + I.x*wi.x + R.y*wr.y + I.y*wi.y
           + R.z*wr.z + I.z*wi.z + R.w*wr.w + I.w*wi.w;
  float i_ = I.x*wr.x - R.x*wi.x + I.y*wr.y - R.y*wi.y
           + I.z*wr.z - R.z*wi.z + I.w*wr.w - R.w*wi.w;
  float t = r_ + i_;
#pragma unroll
  for (int o = 32; o; o >>= 1) t += __shfl_xor(t, o, 64);
  if (lane == 0) out[wid] = 1.f / (1.f + expf(-t));
}

extern "C" void kernel_launch(void* const* d_in, const int* in_sizes, int n_in,
                              void* d_out, int out_size, void* d_ws, size_t ws_size,
                              hipStream_t stream) {
  (void)in_sizes; (void)n_in; (void)out_size; (void)ws_size;
  const float* seq        = (const float*)d_in[0];
  const int*   ppi        = (const int*)d_in[1];
  const int*   ddi        = (const int*)d_in[2];
  const int*   dti        = (const int*)d_in[3];
  const int*   idx1       = (const int*)d_in[4];
  const int*   idx2       = (const int*)d_in[5];
  const float* seq_init_W = (const float*)d_in[6];
  const float* gs1_gcn_W  = (const float*)d_in[7];
  const float* gs1_gcn_b  = (const float*)d_in[8];
  const float* gs1_lin_W  = (const float*)d_in[9];
  const float* gs1_ln_w   = (const float*)d_in[10];
  const float* gs1_ln_b   = (const float*)d_in[11];
  const float* gs2_gcn_W  = (const float*)d_in[12];
  const float* gs2_gcn_b  = (const float*)d_in[13];
  const float* gs2_lin_W  = (const float*)d_in[14];
  const float* gs2_ln_w   = (const float*)d_in[15];
  const float* gs2_ln_b   = (const float*)d_in[16];
  const float* drug_emb   = (const float*)d_in[17];
  const float* prot_emb   = (const float*)d_in[18];
  const float* pp1_W = (const float*)d_in[19]; const float* pp1_b = (const float*)d_in[20];
  const float* td1_W = (const float*)d_in[21]; const float* td1_b = (const float*)d_in[22];
  const float* pr1_W = (const float*)d_in[23]; const float* pr1_b = (const float*)d_in[24];
  const float* dd1_W = (const float*)d_in[25]; const float* dd1_b = (const float*)d_in[26];
  const float* dt1_W = (const float*)d_in[27]; const float* dt1_b = (const float*)d_in[28];
  const float* dr1_W = (const float*)d_in[29]; const float* dr1_b = (const float*)d_in[30];
  const float* pp2_W = (const float*)d_in[31]; const float* pp2_b = (const float*)d_in[32];
  const float* td2_W = (const float*)d_in[33]; const float* td2_b = (const float*)d_in[34];
  const float* pr2_W = (const float*)d_in[35]; const float* pr2_b = (const float*)d_in[36];
  const float* seq_fc_W  = (const float*)d_in[43];
  const float* skip_fc_W = (const float*)d_in[44];
  const float* wR = (const float*)d_in[45];
  const float* wI = (const float*)d_in[46];
  float* outp = (float*)d_out;

  // ---------------- workspace layout ----------------
  char* base = (char*)d_ws;
  unsigned* stgP  = (unsigned*)base;                 // EPPI
  unsigned* stgD  = stgP + EPPI;
  unsigned* stgTD = stgD + EDDI;
  unsigned* stgTP = stgTD + EDTI;
  int* colP  = (int*)(stgTP + EDTI);
  int* colD  = colP + EPPI;
  int* colTD = colD + EDDI;
  int* colTP = colTD + EDTI;
  int* rowptrP  = colTP + EDTI;
  int* rowptrD  = rowptrP + PN + 1;
  int* rowptrTD = rowptrD + PN + 1;
  int* rowptrTP = rowptrTD + PN + 1;
  float* dinvP = (float*)(rowptrTP + PN + 1);
  float* dinvD = dinvP + PN;
  float* icD   = dinvD + PN;
  float* icP   = icD + PN;
  int* bh    = (int*)(icP + PN);                     // 4*NBUCK*NBLKMAX
  int* bbase = bh + 4 * NBUCK * NBLKMAX;             // 4*(NBUCK+1)

  unsigned long long waddr = (unsigned long long)(bbase + 4 * (NBUCK + 1));
  waddr = (waddr + 63ULL) & ~63ULL;
  __bf16* wb = (__bf16*)waddr;
  __bf16* Wseq  = wb;                           // [256,1024]
  __bf16* pair0 = Wseq + 256*1024;              // each pair [512,256]
  __bf16* pair1 = pair0 + 512*256;
  __bf16* pair2 = pair1 + 512*256;
  __bf16* pair3 = pair2 + 512*256;
  __bf16* pair4 = pair3 + 512*256;
  __bf16* sing  = pair4 + 512*256;
  __bf16* Wdt1  = sing;
  __bf16* Wtd1  = sing + 65536;
  __bf16* Wtd2  = sing + 2*65536;
  __bf16* Wsfc  = sing + 3*65536;
  __bf16* Wskp  = sing + 4*65536;
  const size_t NB = (size_t)PN * 256;
  __bf16* Eseq  = sing + 5*65536;               // [20000,1024]
  __bf16* Ed    = Eseq + (size_t)PN*SEQK;
  __bf16* Ep    = Ed + NB;
  __bf16* TL    = Ep + NB;                      // [20000,512]
  __bf16* B0    = TL + (size_t)PN*512;          // x_seq
  __bf16* B2    = B0 + NB;                      // h -> d
  __bf16* B4    = B2 + NB;                      // proj -> fp
  __bf16* B5    = B4 + NB;                      // p
  __bf16* PK    = B5 + NB;                      // [20000][4*256]: x1 | xfp | p2 | xskip

  const dim3 blk(256);
  const dim3 g256(313, 4);
  const dim3 g512(313, 8);
  const dim3 rgrid((PN + 3) / 4);
  const dim3 sgrid(NBLKMAX, 4);
  const dim3 bgrid(NBUCK, 4);

  auto GEMM = [&](const __bf16* X, const __bf16* Wt, const float* bias,
                  __bf16* outb, int K, int ostride, int act, dim3 grid) {
    hipLaunchKernelGGL(gemm_mfma, grid, blk, 0, stream, X, Wt, bias, outb, PN, K, ostride, act);
  };
  auto STAGE = [&](const int* rpG, const int* clG, const float* dv,
                   const float* gb, const float* linb,
                   const int* rpS, const int* clS, const float* ic, const __bf16* Pt,
                   const float* lw, const float* lb, __bf16* o, int ostr, int n, int act) {
    hipLaunchKernelGGL(gcn_combine, rgrid, blk, 0, stream, rpG, clG, dv, TL, 512, gb, linb,
                       TL + 256, rpS, clS, ic, Pt, lw, lb, o, ostr, n, act);
  };

  // ---- converts ----
  {
    WPack p;
    const float* srcs[16] = { seq_init_W, gs1_gcn_W, gs1_lin_W, gs2_gcn_W, gs2_lin_W,
                              dd1_W, dr1_W, pp1_W, pr1_W, pp2_W, pr2_W,
                              dt1_W, td1_W, td2_W, seq_fc_W, skip_fc_W };
    __bf16* dsts[16] = { Wseq, pair0, pair0 + 65536, pair1, pair1 + 65536,
                         pair2, pair2 + 65536, pair3, pair3 + 65536, pair4, pair4 + 65536,
                         Wdt1, Wtd1, Wtd2, Wsfc, Wskp };
    for (int i = 0; i < 16; ++i) { p.src[i] = srcs[i]; p.dst[i] = dsts[i]; p.n[i] = (i == 0) ? 256*1024 : 256*256; }
    hipLaunchKernelGGL(convert_weights, dim3(16, 16), blk, 0, stream, p);
  }
  {
    EPack p;
    p.src[0] = seq;      p.dst[0] = Eseq; p.n[0] = PN * SEQK;
    p.src[1] = drug_emb; p.dst[1] = Ed;   p.n[1] = PN * 256;
    p.src[2] = prot_emb; p.dst[2] = Ep;   p.n[2] = PN * 256;
    hipLaunchKernelGGL(convert_emb, dim3(2048, 3), blk, 0, stream, p);
  }

  // ---- counting-sort CSR build (no global atomics) ----
  GPack g;
  g.src[0] = ppi;        g.dst[0] = ppi + EPPI; g.nE[0] = EPPI;
  g.src[1] = ddi;        g.dst[1] = ddi + EDDI; g.nE[1] = EDDI;
  g.src[2] = dti + EDTI; g.dst[2] = dti;        g.nE[2] = EDTI;
  g.src[3] = dti;        g.dst[3] = dti + EDTI; g.nE[3] = EDTI;
  g.col[0] = colP;  g.col[1] = colD;  g.col[2] = colTD;  g.col[3] = colTP;
  g.rowptr[0] = rowptrP; g.rowptr[1] = rowptrD; g.rowptr[2] = rowptrTD; g.rowptr[3] = rowptrTP;
  g.outdeg[0] = dinvP; g.outdeg[1] = dinvD; g.outdeg[2] = icD; g.outdeg[3] = icP;
  g.stg[0] = stgP; g.stg[1] = stgD; g.stg[2] = stgTD; g.stg[3] = stgTP;
  g.bh = bh; g.bbase = bbase;

  hipLaunchKernelGGL(sort_hist,    sgrid, blk, 0, stream, g);
  hipLaunchKernelGGL(sort_scan,    dim3(1, 4), dim3(1024), 0, stream, g);
  hipLaunchKernelGGL(sort_scatter, sgrid, blk, 0, stream, g);
  hipLaunchKernelGGL(bucket_csr,   bgrid, blk, 0, stream, g);

  // ---- P1: x_seq = relu(Eseq @ Wseq^T) -> B0 ----
  GEMM(Eseq, Wseq, nullptr, B0, SEQK, 256, 1, g256);

  // ---- P2 (gs1): h -> B2 ----
  GEMM(B0, pair0, nullptr, TL, 256, 512, 0, g512);
  STAGE(rowptrP, colP, dinvP, gs1_gcn_b, nullptr, nullptr, nullptr, nullptr, nullptr,
        gs1_ln_w, gs1_ln_b, B2, 256, PN, 1);

  // ---- P3 (gs2): x1 -> PK slot0 ----
  GEMM(B2, pair1, nullptr, TL, 256, 512, 0, g512);
  STAGE(rowptrP, colP, dinvP, gs2_gcn_b, nullptr, nullptr, nullptr, nullptr, nullptr,
        gs2_ln_w, gs2_ln_b, PK + 0, 1024, PN, 0);

  // ---- P4d (drug layer 1): d -> B2 ----
  GEMM(Ed, pair2, nullptr, TL, 256, 512, 0, g512);         // dd1 | dr1
  GEMM(Ep, Wdt1, dt1_b, B4, 256, 256, 0, g256);            // proj_p
  STAGE(rowptrD, colD, dinvD, dd1_b, dr1_b, rowptrTD, colTD, icD, B4,
        nullptr, nullptr, B2, 256, DN, 1);

  // ---- P4p (protein layer 1): p -> B5 ----
  GEMM(Ep, pair3, nullptr, TL, 256, 512, 0, g512);         // pp1 | pr1
  GEMM(Ed, Wtd1, td1_b, B4, 256, 256, 0, g256);            // proj_d
  STAGE(rowptrP, colP, dinvP, pp1_b, pr1_b, rowptrTP, colTP, icP, B4,
        nullptr, nullptr, B5, 256, PN, 1);

  // ---- P5 (protein layer 2): p2 -> PK slot2 ----
  GEMM(B2, Wtd2, td2_b, B4, 256, 256, 0, g256);            // proj (td2) from d
  GEMM(B5, pair4, nullptr, TL, 256, 512, 0, g512);         // pp2 | pr2 from p
  STAGE(rowptrP, colP, dinvP, pp2_b, pr2_b, rowptrTP, colTP, icP, B4,
        nullptr, nullptr, PK + 512, 1024, PN, 0);

  // ---- P6: fuse precompute ----
  hipLaunchKernelGGL(ln_elu, rgrid, blk, 0, stream, B0, B4, PN);  // fp
  GEMM(B4, Wsfc, nullptr, PK + 256, 256, 1024, 2, g256);          // x_fp -> slot1
  GEMM(Ep, Wskp, nullptr, PK + 768, 256, 1024, 0, g256);          // x_skip -> slot3

  // ---- P7: pair epilogue ----
  hipLaunchKernelGGL(pair_kernel, dim3((NPAIRN + 3) / 4), blk, 0, stream,
                     PK, idx1, idx2, wR, wI, outp, NPAIRN);
}